// Round 1
// 662.094 us; speedup vs baseline: 1.0539x; 1.0539x over previous
//
#include <hip/hip_runtime.h>
#include <math.h>

#define B_   16
#define C_   512
#define N_   1681
#define Np   1792      // padded N (multiple of 128)
#define CK_  256
#define EPSV 1e-5f
#define SCALE 0.0625f  // Ck^-0.5

typedef __bf16 bf16x8 __attribute__((ext_vector_type(8)));
typedef __bf16 bf16x4 __attribute__((ext_vector_type(4)));
typedef float  f32x4  __attribute__((ext_vector_type(4)));

// ---------------------------------------------------------------------------
// Stage a 128-row x 64-bf16 (128 B) tile global->LDS via async 16B loads.
// LDS chunk (row, col) holds global chunk (row, col ^ (row&7))  [xor swizzle]
// ---------------------------------------------------------------------------
__device__ __forceinline__
void stage_tile(const char* gbase, int ld_bytes, char* lds, int w, int lane)
{
    #pragma unroll
    for (int i = 0; i < 4; ++i) {
        int chunk = (i * 4 + w) * 64 + lane;       // 0..1023
        int row   = chunk >> 3;                    // 8 chunks (128B) per row
        int col   = chunk & 7;
        int scol  = col ^ (row & 7);
        const char* g = gbase + (size_t)row * ld_bytes + scol * 16;
        char* l = lds + (size_t)(i * 4 + w) * 1024;  // wave-uniform base
        __builtin_amdgcn_global_load_lds(
            (const __attribute__((address_space(1))) void*)g,
            (__attribute__((address_space(3))) void*)l, 16, 0, 0);
    }
}

// ---------------------------------------------------------------------------
// 128x128 tile MFMA core: As/Bs are [128 rows][64 k] bf16, xor-swizzled.
// Wave w (0..3): wr=w>>1 selects A-row half, wc=w&1 selects B-row half.
// ---------------------------------------------------------------------------
__device__ __forceinline__
void mma_tile(const __bf16* As, const __bf16* Bs, f32x4 acc[4][4], int wr, int wc, int lane)
{
    const int l15 = lane & 15, quad = lane >> 4;
    #pragma unroll
    for (int kk = 0; kk < 2; ++kk) {
        bf16x8 af[4], bfr[4];
        #pragma unroll
        for (int i = 0; i < 4; ++i) {
            int row = wr * 64 + i * 16 + l15;
            int c   = (kk * 4 + quad) ^ (row & 7);
            af[i] = *(const bf16x8*)(As + row * 64 + c * 8);
        }
        #pragma unroll
        for (int j = 0; j < 4; ++j) {
            int row = wc * 64 + j * 16 + l15;
            int c   = (kk * 4 + quad) ^ (row & 7);
            bfr[j] = *(const bf16x8*)(Bs + row * 64 + c * 8);
        }
        #pragma unroll
        for (int i = 0; i < 4; ++i)
            #pragma unroll
            for (int j = 0; j < 4; ++j)
                acc[i][j] = __builtin_amdgcn_mfma_f32_16x16x32_bf16(
                    af[i], bfr[j], acc[i][j], 0, 0, 0);
    }
}

// ---------------------------------------------------------------------------
// cvt_w: Wh[512][512] bf16 = [Wq; Wk], b2[512] f32 = [bq; bk]
// ---------------------------------------------------------------------------
__global__ __launch_bounds__(256)
void cvt_w_kernel(const float* __restrict__ Wq, const float* __restrict__ Wk,
                  const float* __restrict__ bq, const float* __restrict__ bk,
                  __bf16* __restrict__ Wh, float* __restrict__ b2)
{
    int idx = blockIdx.x * 1024 + threadIdx.x * 4;
    #pragma unroll
    for (int p = 0; p < 4; ++p) {
        int e = idx + p;
        int row = e >> 9, col = e & 511;
        float v = (row < 256) ? Wq[row * 512 + col] : Wk[(row - 256) * 512 + col];
        Wh[e] = (__bf16)v;
    }
    if (blockIdx.x == 0) {
        int t = threadIdx.x;
        b2[t]       = bq[t];
        b2[256 + t] = bk[t];
    }
}

// ---------------------------------------------------------------------------
// cvt_x: xh[b][c][n<Np] bf16 (zero pad), xt[b][n<Np][c] bf16 (zero pad rows)
// ---------------------------------------------------------------------------
__global__ __launch_bounds__(256)
void cvt_x_kernel(const float* __restrict__ x,
                  __bf16* __restrict__ xh, __bf16* __restrict__ xt)
{
    __shared__ float tile[32][33];
    const int t = threadIdx.x;
    const int n0 = blockIdx.x * 32, c0 = blockIdx.y * 32, b = blockIdx.z;
    const float* xb = x + (size_t)b * C_ * N_;
    #pragma unroll
    for (int p = 0; p < 4; ++p) {
        int lin = p * 256 + t;
        int i = lin >> 5, j = lin & 31;     // i: c-offset, j: n-offset
        int n = n0 + j;
        float v = (n < N_) ? xb[(size_t)(c0 + i) * N_ + n] : 0.0f;
        tile[i][j] = v;
        xh[(size_t)b * C_ * Np + (size_t)(c0 + i) * Np + n] = (__bf16)v;
    }
    __syncthreads();
    #pragma unroll
    for (int p = 0; p < 4; ++p) {
        int lin = p * 256 + t;
        int i = lin >> 5, j = lin & 31;     // i: n-offset, j: c-offset
        xt[(size_t)b * Np * C_ + (size_t)(n0 + i) * C_ + (c0 + j)] = (__bf16)tile[j][i];
    }
}

// ---------------------------------------------------------------------------
// proj: QKt[b][n][k2] = sum_c xt[b][n][c] * Wh[k2][c] + b2[k2]
// grid (14 n-tiles, 4 k2-tiles, B)
// ---------------------------------------------------------------------------
__global__ __launch_bounds__(256)
void proj_kernel(const __bf16* __restrict__ xt, const __bf16* __restrict__ Wh,
                 const float* __restrict__ b2, __bf16* __restrict__ QKt)
{
    __shared__ __bf16 As[128 * 64];
    __shared__ __bf16 Bs[128 * 64];
    const int t = threadIdx.x, w = t >> 6, lane = t & 63;
    const int n0 = blockIdx.x * 128, k20 = blockIdx.y * 128, b = blockIdx.z;
    const char* Abase = (const char*)xt + ((size_t)b * Np + n0) * (C_ * 2);
    const char* Bbase = (const char*)Wh + (size_t)k20 * (C_ * 2);

    f32x4 acc[4][4] = {};
    for (int k0 = 0; k0 < C_; k0 += 64) {
        stage_tile(Abase + k0 * 2, C_ * 2, (char*)As, w, lane);
        stage_tile(Bbase + k0 * 2, C_ * 2, (char*)Bs, w, lane);
        __syncthreads();
        mma_tile(As, Bs, acc, w >> 1, w & 1, lane);
        __syncthreads();
    }
    const int l15 = lane & 15, quad = lane >> 4;
    __bf16* ob = QKt + (size_t)b * Np * 512;
    #pragma unroll
    for (int j = 0; j < 4; ++j) {
        int k2 = k20 + (w & 1) * 64 + j * 16 + l15;
        float bias = b2[k2];
        #pragma unroll
        for (int i = 0; i < 4; ++i)
            #pragma unroll
            for (int r = 0; r < 4; ++r) {
                int n = n0 + (w >> 1) * 64 + i * 16 + quad * 4 + r;
                ob[(size_t)n * 512 + k2] = (__bf16)(acc[i][j][r] + bias);
            }
    }
}

// ---------------------------------------------------------------------------
// sim: S[b][n][m] = SCALE * sum_k Qt[n][k] * Kt[m][k]
// Qt = QKt[:, 0:256], Kt = QKt[:, 256:512].  grid (14 m, 14 n, B)
// ---------------------------------------------------------------------------
__global__ __launch_bounds__(256)
void sim_kernel(const __bf16* __restrict__ QKt, __bf16* __restrict__ S)
{
    __shared__ __bf16 As[128 * 64];
    __shared__ __bf16 Bs[128 * 64];
    const int t = threadIdx.x, w = t >> 6, lane = t & 63;
    const int m0 = blockIdx.x * 128, n0 = blockIdx.y * 128, b = blockIdx.z;
    const char* base = (const char*)QKt + (size_t)b * Np * 1024;
    const char* Abase = base + (size_t)n0 * 1024;          // Qt rows
    const char* Bbase = base + (size_t)m0 * 1024 + 512;    // Kt rows (+256 elems)

    f32x4 acc[4][4] = {};
    for (int k0 = 0; k0 < CK_; k0 += 64) {
        stage_tile(Abase + k0 * 2, 1024, (char*)As, w, lane);
        stage_tile(Bbase + k0 * 2, 1024, (char*)Bs, w, lane);
        __syncthreads();
        mma_tile(As, Bs, acc, w >> 1, w & 1, lane);
        __syncthreads();
    }
    const int l15 = lane & 15, quad = lane >> 4;
    __bf16* Sb = S + (size_t)b * Np * Np;
    #pragma unroll
    for (int i = 0; i < 4; ++i)
        #pragma unroll
        for (int r = 0; r < 4; ++r) {
            int n = n0 + (w >> 1) * 64 + i * 16 + quad * 4 + r;
            #pragma unroll
            for (int j = 0; j < 4; ++j) {
                int m = m0 + (w & 1) * 64 + j * 16 + l15;
                Sb[(size_t)n * Np + m] = (__bf16)(acc[i][j][r] * SCALE);
            }
        }
}

// ---------------------------------------------------------------------------
// norm v2: one WAVE per row, register-resident, fully vectorized, no LDS,
// no __syncthreads.  Single sweep computes min(s*f), A=sum(s*f^2), F=sum(f);
// sum_x1 = A - min*F (algebraically identical to sum((s*f-min)*f)).
// Then one store sweep: out = (s*f - min)*f*inv + bg   (0 in the pad).
// ---------------------------------------------------------------------------
__global__ __launch_bounds__(256, 4)
void norm_kernel(const float* __restrict__ fg, const float* __restrict__ bg,
                 __bf16* __restrict__ S)
{
    const int t = threadIdx.x;
    const int wid = t >> 6, lane = t & 63;
    const int n = blockIdx.x * 4 + wid;
    const int b = blockIdx.y;
    if (n >= N_) return;

    __bf16* Srow = S + (size_t)b * Np * Np + (size_t)n * Np;
    const float* fgrow = fg + ((size_t)b * N_ + n) * N_;
    const float* bgrow = bg + ((size_t)b * N_ + n) * N_;

    float sv[7][4];   // s * f
    float fv[7][4];   // f
    float lmin = INFINITY, aSum = 0.0f, fSum = 0.0f;

    #pragma unroll
    for (int i = 0; i < 7; ++i) {
        const int m0 = i * 256 + lane * 4;
        bf16x4 sr = *(const bf16x4*)(Srow + m0);       // 8B, always in-bounds (padded)
        f32x4 f;
        if (m0 + 4 <= N_) {
            f = *(const f32x4*)(fgrow + m0);           // 16B vector load
        } else {
            f[0] = (m0 + 0 < N_) ? fgrow[m0 + 0] : 0.0f;
            f[1] = (m0 + 1 < N_) ? fgrow[m0 + 1] : 0.0f;
            f[2] = (m0 + 2 < N_) ? fgrow[m0 + 2] : 0.0f;
            f[3] = (m0 + 3 < N_) ? fgrow[m0 + 3] : 0.0f;
        }
        #pragma unroll
        for (int k = 0; k < 4; ++k) {
            const bool valid = (m0 + k) < N_;
            const float fk = f[k];                     // 0 for invalid (guarded above)
            const float svk = (float)sr[k] * fk;       // invalid: finite*0 = 0
            sv[i][k] = svk;
            fv[i][k] = fk;
            aSum += svk * fk;
            fSum += fk;
            lmin = fminf(lmin, valid ? svk : INFINITY);
        }
    }

    // wave-wide butterfly reductions (no cross-wave: one wave owns the row)
    #pragma unroll
    for (int off = 1; off < 64; off <<= 1) {
        lmin = fminf(lmin, __shfl_xor(lmin, off, 64));
        aSum += __shfl_xor(aSum, off, 64);
        fSum += __shfl_xor(fSum, off, 64);
    }
    const float inv = 1.0f / ((aSum - lmin * fSum) + EPSV);

    #pragma unroll
    for (int i = 0; i < 7; ++i) {
        const int m0 = i * 256 + lane * 4;
        f32x4 g;
        if (m0 + 4 <= N_) {
            g = *(const f32x4*)(bgrow + m0);
        } else {
            g[0] = (m0 + 0 < N_) ? bgrow[m0 + 0] : 0.0f;
            g[1] = (m0 + 1 < N_) ? bgrow[m0 + 1] : 0.0f;
            g[2] = (m0 + 2 < N_) ? bgrow[m0 + 2] : 0.0f;
            g[3] = (m0 + 3 < N_) ? bgrow[m0 + 3] : 0.0f;
        }
        bf16x4 o;
        #pragma unroll
        for (int k = 0; k < 4; ++k) {
            const bool valid = (m0 + k) < N_;
            const float x1 = (sv[i][k] - lmin) * fv[i][k];
            o[k] = (__bf16)(valid ? (x1 * inv + g[k]) : 0.0f);
        }
        *(bf16x4*)(Srow + m0) = o;                     // 8B store, covers pad too
    }
}

// ---------------------------------------------------------------------------
// ctx: out[b][c][n] = gamma * sum_m xh[c][m] * A'[n][m] + x[b][c][n]
// grid (4 c-tiles, 14 n-tiles, B)
// ---------------------------------------------------------------------------
__global__ __launch_bounds__(256)
void ctx_kernel(const __bf16* __restrict__ xh, const __bf16* __restrict__ Ap,
                const float* __restrict__ x, const float* __restrict__ gamma,
                float* __restrict__ out)
{
    __shared__ __bf16 As[128 * 64];
    __shared__ __bf16 Bs[128 * 64];
    const int t = threadIdx.x, w = t >> 6, lane = t & 63;
    const int c0 = blockIdx.x * 128, n0 = blockIdx.y * 128, b = blockIdx.z;
    const char* Abase = (const char*)xh + ((size_t)b * C_ + c0) * (Np * 2);
    const char* Bbase = (const char*)Ap + ((size_t)b * Np + n0) * (Np * 2);

    f32x4 acc[4][4] = {};
    for (int k0 = 0; k0 < Np; k0 += 64) {
        stage_tile(Abase + k0 * 2, Np * 2, (char*)As, w, lane);
        stage_tile(Bbase + k0 * 2, Np * 2, (char*)Bs, w, lane);
        __syncthreads();
        mma_tile(As, Bs, acc, w >> 1, w & 1, lane);
        __syncthreads();
    }
    const int l15 = lane & 15, quad = lane >> 4;
    const float g = gamma[0];
    const float* xb = x + (size_t)b * C_ * N_;
    float* ob = out + (size_t)b * C_ * N_;
    #pragma unroll
    for (int i = 0; i < 4; ++i)
        #pragma unroll
        for (int r = 0; r < 4; ++r) {
            int c = c0 + (w >> 1) * 64 + i * 16 + quad * 4 + r;
            #pragma unroll
            for (int j = 0; j < 4; ++j) {
                int n = n0 + (w & 1) * 64 + j * 16 + l15;
                if (n < N_) {
                    size_t idx = (size_t)c * N_ + n;
                    ob[idx] = g * acc[i][j][r] + xb[idx];
                }
            }
        }
}

// ---------------------------------------------------------------------------
extern "C" void kernel_launch(void* const* d_in, const int* in_sizes, int n_in,
                              void* d_out, int out_size, void* d_ws, size_t ws_size,
                              hipStream_t stream)
{
    const float* x     = (const float*)d_in[0];
    const float* fg    = (const float*)d_in[1];
    const float* bg    = (const float*)d_in[2];
    const float* Wq    = (const float*)d_in[3];
    const float* bq    = (const float*)d_in[4];
    const float* Wk    = (const float*)d_in[5];
    const float* bk    = (const float*)d_in[6];
    const float* gamma = (const float*)d_in[7];
    float* out = (float*)d_out;

    char* p = (char*)d_ws;
    __bf16* xh  = (__bf16*)p; p += (size_t)B_ * C_ * Np * 2;   // 29.4 MB
    __bf16* xt  = (__bf16*)p; p += (size_t)B_ * Np * C_ * 2;   // 29.4 MB
    __bf16* QKt = (__bf16*)p; p += (size_t)B_ * Np * 512 * 2;  // 29.4 MB
    __bf16* S   = (__bf16*)p; p += (size_t)B_ * Np * Np * 2;   // 102.8 MB
    __bf16* Wh  = (__bf16*)p; p += (size_t)512 * 512 * 2;      // 0.5 MB
    float*  b2  = (float*)p;                                   // 2 KB

    cvt_w_kernel<<<dim3(256), dim3(256), 0, stream>>>(Wq, Wk, bq, bk, Wh, b2);
    cvt_x_kernel<<<dim3(Np / 32, C_ / 32, B_), dim3(256), 0, stream>>>(x, xh, xt);
    proj_kernel<<<dim3(Np / 128, 4, B_), dim3(256), 0, stream>>>(xt, Wh, b2, QKt);
    sim_kernel<<<dim3(Np / 128, Np / 128, B_), dim3(256), 0, stream>>>(QKt, S);
    norm_kernel<<<dim3((N_ + 3) / 4, B_), dim3(256), 0, stream>>>(fg, bg, S);
    ctx_kernel<<<dim3(C_ / 128, Np / 128, B_), dim3(256), 0, stream>>>(xh, S, x, gamma, out);
}